// Round 4
// baseline (463.272 us; speedup 1.0000x reference)
//
#include <hip/hip_runtime.h>
#include <math.h>

#define BPIX 64      // pixels per block (one row segment: 320 = 5*64)
#define HW   76800   // H*W
#define W_   320
#define H_   240
#define ENC_W 160
#define ENC_H 120
#define CENC 64
#define CSEG 21
#define NCH  85      // CENC + CSEG
#define ROW  90      // 2 + 85 + 3
#define PIXF 630     // 7 * 90
#define TPLS 94      // template row stride in floats (even -> 8B-aligned pairs)
#define NF4  10080   // BPIX*PIXF/4 float4 per block

typedef float f4v __attribute__((ext_vector_type(4)));

// ---------------------------------------------------------------------------
// Per-batch constants: K_inv (16), c2f translation -fmin/VOXEL (3), pad_off (3)
// ---------------------------------------------------------------------------
__global__ void setup_consts_kernel(const float* __restrict__ intr,
                                    float* __restrict__ C) {
  int b = threadIdx.x;
  if (b >= 2) return;
  float A[4][4], inv[4][4];
  for (int r = 0; r < 4; ++r)
    for (int c = 0; c < 4; ++c) {
      A[r][c] = intr[b * 16 + r * 4 + c];
      inv[r][c] = (r == c) ? 1.f : 0.f;
    }
  for (int k = 0; k < 4; ++k) {
    int piv = k; float best = fabsf(A[k][k]);
    for (int r = k + 1; r < 4; ++r) {
      float v = fabsf(A[r][k]);
      if (v > best) { best = v; piv = r; }
    }
    if (piv != k) {
      for (int c = 0; c < 4; ++c) {
        float t = A[k][c]; A[k][c] = A[piv][c]; A[piv][c] = t;
        t = inv[k][c]; inv[k][c] = inv[piv][c]; inv[piv][c] = t;
      }
    }
    float ip = 1.f / A[k][k];
    for (int c = 0; c < 4; ++c) { A[k][c] *= ip; inv[k][c] *= ip; }
    for (int r = 0; r < 4; ++r) if (r != k) {
      float f = A[r][k];
      for (int c = 0; c < 4; ++c) { A[r][c] -= f * A[k][c]; inv[r][c] -= f * inv[k][c]; }
    }
  }
  const float cpx[4][2] = {{0.f, 0.f}, {320.f, 0.f}, {0.f, 240.f}, {320.f, 240.f}};
  float fmn[3] = {1e30f, 1e30f, 1e30f}, fmx[3] = {-1e30f, -1e30f, -1e30f};
  for (int zi = 0; zi < 2; ++zi) {
    float z = zi ? 6.0f : 0.4f;
    for (int i = 0; i < 4; ++i) {
      float px = cpx[i][0] * z, py = cpx[i][1] * z;
      for (int ax = 0; ax < 3; ++ax) {
        float v = inv[ax][0] * px + inv[ax][1] * py + inv[ax][2] * z + inv[ax][3];
        fmn[ax] = fminf(fmn[ax], v);
        fmx[ax] = fmaxf(fmx[ax], v);
      }
    }
  }
  float* Cb = C + b * 32;
  for (int r = 0; r < 4; ++r)
    for (int c = 0; c < 4; ++c) Cb[r * 4 + c] = inv[r][c];
  for (int ax = 0; ax < 3; ++ax) {
    Cb[16 + ax] = -fmn[ax] / 0.03f;
    Cb[19 + ax] = (256.0f - (fmx[ax] - fmn[ax]) / 0.03f) * 0.5f;
  }
}

// ---------------------------------------------------------------------------
// Main kernel, 256 threads / 64 pixels.
// Phase 0 (parallel 3-way): grp0 projection+mask+per-rep specials,
//                           grp1 enc bilinear taps, grp2 seg bilinear taps.
// Phase 1: tpl[p][2+ch] = bilinear * m  (lanes=pixels -> coalesced gathers)
// Phase 2: float4 nontemporal stream; fast path = 2x ds_read_b64 from tpl.
// ---------------------------------------------------------------------------
__global__ __launch_bounds__(256) void sparse_proj_kernel(
    const float* __restrict__ depth, const float* __restrict__ enc,
    const float* __restrict__ seg, const float* __restrict__ C,
    float* __restrict__ out) {
  __shared__ float  tpl[BPIX * TPLS];   // c=2..86 samp, 87 fcx, 88 fcy
  __shared__ float2 sd[BPIX * 7];       // (sign, abs) per (pixel, rep)
  __shared__ float  fcz[BPIX * 7];      // fc_z per (pixel, rep)
  __shared__ float  mArr[BPIX];
  __shared__ int    eo0[BPIX], eo1[BPIX], eo2[BPIX], eo3[BPIX];
  __shared__ float  ew0[BPIX], ew1[BPIX], ew2[BPIX], ew3[BPIX];
  __shared__ int    so0[BPIX], so1[BPIX], so2[BPIX], so3[BPIX];
  __shared__ float  sw0[BPIX], sw1[BPIX], sw2[BPIX], sw3[BPIX];

  const int tid = threadIdx.x;
  const int bx  = blockIdx.x;
  const int b   = blockIdx.y;
  const float* Cb = C + b * 32;
  const int x0 = (bx % 5) * 64;   // all 64 pixels share one image row
  const int yrow = bx / 5;

  const int grp = tid >> 6;
  const int p   = tid & 63;

  if (grp == 0) {
    // projection, mask, per-rep specials
    const float d = depth[(size_t)b * HW + bx * BPIX + p];
    const bool val = (d >= 0.4f) && (d <= 6.0f);
    const float m = val ? 1.f : 0.f;
    const float z = val ? d : 0.f;
    const float nx = (float)(x0 + p) / 320.f;
    const float ny = (float)yrow / 240.f;
    const float xv = nx * 320.f * z;   // replicate reference rounding path
    const float yv = ny * 240.f * z;
    const float q0 = Cb[0] * xv + Cb[1] * yv + Cb[2] * z + Cb[3];
    const float q1 = Cb[4] * xv + Cb[5] * yv + Cb[6] * z + Cb[7];
    const float q2 = Cb[8] * xv + Cb[9] * yv + Cb[10] * z + Cb[11];
    const float q3 = Cb[12] * xv + Cb[13] * yv + Cb[14] * z + Cb[15];
    const float INV_V = (float)(1.0 / 0.03);
    const float gcx = q0 * INV_V + Cb[16] * q3;
    const float gcy = q1 * INV_V + Cb[17] * q3;
    const float gcz = q2 * INV_V + Cb[18] * q3;
    mArr[p] = m;
    tpl[p * TPLS + 87] = (gcx + Cb[19]) * m;
    tpl[p * TPLS + 88] = (gcy + Cb[20]) * m;
    const float fr = gcz - truncf(gcz);
    const float fz = (gcz + Cb[21]) * m;
#pragma unroll
    for (int r = 0; r < 7; ++r) {
      const float df = fr + (float)(r - 3);
      const float s = (df > 0.f) ? 1.f : ((df < 0.f) ? -1.f : 0.f);
      sd[p * 7 + r] = make_float2(s * m, fabsf(df) * m);
      fcz[p * 7 + r] = fz + (float)(r - 3) * m;
    }
  } else if (grp == 1) {
    // encoder taps on 160x120
    const float nx = (float)(x0 + p) / 320.f;
    const float ny = (float)yrow / 240.f;
    const float ix = nx * 160.f - 0.5f;
    const float iy = ny * 120.f - 0.5f;
    const float x0f = floorf(ix), y0f = floorf(iy);
    const float wx = ix - x0f, wy = iy - y0f;
    const int xi0 = (int)x0f, yi0 = (int)y0f;
    const int xi1 = xi0 + 1, yi1 = yi0 + 1;
    const float vx0 = (xi0 >= 0 && xi0 < ENC_W) ? 1.f : 0.f;
    const float vx1 = (xi1 >= 0 && xi1 < ENC_W) ? 1.f : 0.f;
    const float vy0 = (yi0 >= 0 && yi0 < ENC_H) ? 1.f : 0.f;
    const float vy1 = (yi1 >= 0 && yi1 < ENC_H) ? 1.f : 0.f;
    const int xc0 = min(max(xi0, 0), ENC_W - 1), xc1 = min(max(xi1, 0), ENC_W - 1);
    const int yc0 = min(max(yi0, 0), ENC_H - 1), yc1 = min(max(yi1, 0), ENC_H - 1);
    eo0[p] = yc0 * ENC_W + xc0; ew0[p] = (1.f - wx) * (1.f - wy) * vx0 * vy0;
    eo1[p] = yc0 * ENC_W + xc1; ew1[p] = wx * (1.f - wy) * vx1 * vy0;
    eo2[p] = yc1 * ENC_W + xc0; ew2[p] = (1.f - wx) * wy * vx0 * vy1;
    eo3[p] = yc1 * ENC_W + xc1; ew3[p] = wx * wy * vx1 * vy1;
  } else if (grp == 2) {
    // seg taps on 320x240
    const float nx = (float)(x0 + p) / 320.f;
    const float ny = (float)yrow / 240.f;
    const float ix = nx * 320.f - 0.5f;
    const float iy = ny * 240.f - 0.5f;
    const float x0f = floorf(ix), y0f = floorf(iy);
    const float wx = ix - x0f, wy = iy - y0f;
    const int xi0 = (int)x0f, yi0 = (int)y0f;
    const int xi1 = xi0 + 1, yi1 = yi0 + 1;
    const float vx0 = (xi0 >= 0 && xi0 < W_) ? 1.f : 0.f;
    const float vx1 = (xi1 >= 0 && xi1 < W_) ? 1.f : 0.f;
    const float vy0 = (yi0 >= 0 && yi0 < H_) ? 1.f : 0.f;
    const float vy1 = (yi1 >= 0 && yi1 < H_) ? 1.f : 0.f;
    const int xc0 = min(max(xi0, 0), W_ - 1), xc1 = min(max(xi1, 0), W_ - 1);
    const int yc0 = min(max(yi0, 0), H_ - 1), yc1 = min(max(yi1, 0), H_ - 1);
    so0[p] = yc0 * W_ + xc0; sw0[p] = (1.f - wx) * (1.f - wy) * vx0 * vy0;
    so1[p] = yc0 * W_ + xc1; sw1[p] = wx * (1.f - wy) * vx1 * vy0;
    so2[p] = yc1 * W_ + xc0; sw2[p] = (1.f - wx) * wy * vx0 * vy1;
    so3[p] = yc1 * W_ + xc1; sw3[p] = wx * wy * vx1 * vy1;
  }
  __syncthreads();

  // Phase 1: lanes = pixels (coalesced taps), loop over 85 channels
  for (int idx = tid; idx < BPIX * NCH; idx += 256) {
    const int pp = idx & (BPIX - 1);
    const int ch = idx >> 6;   // wave-uniform
    float v;
    if (ch < CENC) {
      const float* fb = enc + ((size_t)b * CENC + ch) * (ENC_H * ENC_W);
      v = ew0[pp] * fb[eo0[pp]] + ew1[pp] * fb[eo1[pp]] +
          ew2[pp] * fb[eo2[pp]] + ew3[pp] * fb[eo3[pp]];
    } else {
      const float* fb = seg + ((size_t)b * CSEG + (ch - CENC)) * (size_t)HW;
      v = sw0[pp] * fb[so0[pp]] + sw1[pp] * fb[so1[pp]] +
          sw2[pp] * fb[so2[pp]] + sw3[pp] * fb[so3[pp]];
    }
    tpl[pp * TPLS + 2 + ch] = v * mArr[pp];
  }
  __syncthreads();

  // Phase 2: float4 nontemporal stream of the block's contiguous 161280B chunk.
  // Exact mul-shift decodes: p=(e*53262)>>25 (e<40320), r=(w*729)>>16 (w<630).
  f4v* out4 = reinterpret_cast<f4v*>(out + (size_t)(b * HW + bx * BPIX) * PIXF);
  for (int j = tid; j < NF4; j += 256) {
    const unsigned e0 = (unsigned)j << 2;
    const int pq = (int)((e0 * 53262u) >> 25);
    const int w  = (int)e0 - pq * 630;
    const int r  = (int)(((unsigned)w * 729u) >> 16);
    const int c  = w - r * 90;          // even
    f4v v;
    if ((unsigned)(c - 2) <= 83u) {
      // c..c+3 within [2,88]: straight template copy (8B-aligned: pq*94+c even)
      const float2* t = reinterpret_cast<const float2*>(&tpl[pq * TPLS + c]);
      const float2 a = t[0];
      const float2 bq = t[1];
      v.x = a.x; v.y = a.y; v.z = bq.x; v.w = bq.y;
    } else {
      // boundary float4 (c in {0, 86, 88}): generic per-element decode
#pragma unroll
      for (int k = 0; k < 4; ++k) {
        const unsigned e = e0 + (unsigned)k;
        const int pk = (int)((e * 53262u) >> 25);
        const int wk = (int)e - pk * 630;
        const int rk = (int)(((unsigned)wk * 729u) >> 16);
        const int ck = wk - rk * 90;
        float val;
        if (ck == 0)       val = sd[pk * 7 + rk].x;
        else if (ck == 1)  val = sd[pk * 7 + rk].y;
        else if (ck == 89) val = fcz[pk * 7 + rk];
        else               val = tpl[pk * TPLS + ck];
        v[k] = val;
      }
    }
    __builtin_nontemporal_store(v, &out4[j]);
  }
}

extern "C" void kernel_launch(void* const* d_in, const int* in_sizes, int n_in,
                              void* d_out, int out_size, void* d_ws, size_t ws_size,
                              hipStream_t stream) {
  const float* depth = (const float*)d_in[0];
  const float* enc   = (const float*)d_in[1];
  const float* seg   = (const float*)d_in[2];
  const float* intr  = (const float*)d_in[3];
  float* out = (float*)d_out;
  float* C   = (float*)d_ws;   // 2 * 32 floats

  setup_consts_kernel<<<1, 64, 0, stream>>>(intr, C);
  dim3 grid(HW / BPIX, 2);
  sparse_proj_kernel<<<grid, 256, 0, stream>>>(depth, enc, seg, C, out);
}